// Round 1
// baseline (6397.085 us; speedup 1.0000x reference)
//
#include <hip/hip_runtime.h>
#include <math.h>

#define NN 100000
#define NE 3200000
#define NEG 0.2f

__device__ __forceinline__ float leaky(float v) { return v > 0.f ? v : NEG * v; }

// ---------------------------------------------------------------------------
// k0: attention constants for layer 1:
//   cs[h] = dot(W1[h*32:(h+1)*32], att_src1[h]), cd[h] likewise. c4 = {cs0,cs1,cd0,cd1}
__global__ void k0_consts(const float* __restrict__ W1, const float* __restrict__ as1,
                          const float* __restrict__ ad1, float* __restrict__ c4) {
    int h = threadIdx.x;
    if (h < 2) {
        float cs = 0.f, cd = 0.f;
        for (int c = 0; c < 32; ++c) {
            float w = W1[h * 32 + c];
            cs += w * as1[h * 32 + c];
            cd += w * ad1[h * 32 + c];
        }
        c4[h] = cs;
        c4[2 + h] = cd;
    }
}

// ---------------------------------------------------------------------------
// k1: init layer-1 softmax accumulators with the self-loop contribution.
//   sT[n] = {s_h0, s_h1, T_h0, T_h1}; s = sum exp(e), T = sum exp(e)*x[src]
__global__ void __launch_bounds__(256) k1_init(const float* __restrict__ x,
                                               const float* __restrict__ c4,
                                               float* __restrict__ sT) {
    int n = blockIdx.x * blockDim.x + threadIdx.x;
    if (n >= NN) return;
    float xv = x[n];
    float ex0 = __expf(leaky(xv * (c4[0] + c4[2])));
    float ex1 = __expf(leaky(xv * (c4[1] + c4[3])));
    ((float4*)sT)[n] = make_float4(ex0, ex1, ex0 * xv, ex1 * xv);
}

// ---------------------------------------------------------------------------
// k2: layer-1 edge pass. e_h = leaky(x[s]*cs_h + x[d]*cd_h); scatter exp sums.
__global__ void __launch_bounds__(256) k2_edge1(const int* __restrict__ ei,
                                                const float* __restrict__ x,
                                                const float* __restrict__ c4,
                                                float* __restrict__ sT) {
    int e = blockIdx.x * blockDim.x + threadIdx.x;
    if (e >= NE) return;
    int s = ei[e], d = ei[NE + e];
    float xs = x[s], xd = x[d];
    float ex0 = __expf(leaky(xs * c4[0] + xd * c4[2]));
    float ex1 = __expf(leaky(xs * c4[1] + xd * c4[3]));
    float* p = sT + (size_t)d * 4;
    atomicAdd(p + 0, ex0);
    atomicAdd(p + 1, ex1);
    atomicAdd(p + 2, ex0 * xs);
    atomicAdd(p + 3, ex1 * xs);
}

// ---------------------------------------------------------------------------
// k3: per-node: layer-1 output (64), h2 = out1 @ W2 (32), layer-2 attention
//     scalars, and self-loop init of layer-2 softmax accumulators.
__global__ void __launch_bounds__(256) k3_node(const float* __restrict__ sT,
                                               const float* __restrict__ W1,
                                               const float* __restrict__ b1,
                                               const float* __restrict__ W2,
                                               const float* __restrict__ as2,
                                               const float* __restrict__ ad2,
                                               float* __restrict__ h2g,
                                               float2* __restrict__ a2,
                                               float* __restrict__ s2,
                                               float* __restrict__ U2) {
    int n = blockIdx.x * blockDim.x + threadIdx.x;
    if (n >= NN) return;
    float4 st = ((const float4*)sT)[n];
    float r0 = st.z / (st.x + 1e-16f);
    float r1 = st.w / (st.y + 1e-16f);
    float h2[32];
#pragma unroll
    for (int c = 0; c < 32; ++c) h2[c] = 0.f;
    for (int j = 0; j < 64; ++j) {
        float o = W1[j] * (j < 32 ? r0 : r1) + b1[j];
        o = fmaxf(o, 0.f);
#pragma unroll
        for (int c = 0; c < 32; ++c) h2[c] += o * W2[j * 32 + c];
    }
    float asum = 0.f, adsum = 0.f;
#pragma unroll
    for (int c = 0; c < 32; ++c) {
        asum += h2[c] * as2[c];
        adsum += h2[c] * ad2[c];
    }
    float es = __expf(leaky(asum + adsum));
    s2[n] = es;
    a2[n] = make_float2(asum, adsum);
    float4* hg = (float4*)(h2g + (size_t)n * 32);
    float4* ug = (float4*)(U2 + (size_t)n * 32);
#pragma unroll
    for (int q = 0; q < 8; ++q) {
        float4 v = make_float4(h2[q * 4], h2[q * 4 + 1], h2[q * 4 + 2], h2[q * 4 + 3]);
        hg[q] = v;
        ug[q] = make_float4(v.x * es, v.y * es, v.z * es, v.w * es);
    }
}

// ---------------------------------------------------------------------------
// k4: layer-2 edge pass. ex = exp(leaky(a_src[s] + a_dst[d])); scatter ex and
//     ex * h2[s, :] into per-dst accumulators.
__global__ void __launch_bounds__(256) k4_edge2(const int* __restrict__ ei,
                                                const float* __restrict__ h2g,
                                                const float2* __restrict__ a2,
                                                float* __restrict__ s2,
                                                float* __restrict__ U2) {
    int e = blockIdx.x * blockDim.x + threadIdx.x;
    if (e >= NE) return;
    int s = ei[e], d = ei[NE + e];
    float ex = __expf(leaky(a2[s].x + a2[d].y));
    atomicAdd(s2 + d, ex);
    const float4* hs = (const float4*)(h2g + (size_t)s * 32);
    float* ud = U2 + (size_t)d * 32;
#pragma unroll
    for (int q = 0; q < 8; ++q) {
        float4 v = hs[q];
        atomicAdd(ud + q * 4 + 0, ex * v.x);
        atomicAdd(ud + q * 4 + 1, ex * v.y);
        atomicAdd(ud + q * 4 + 2, ex * v.z);
        atomicAdd(ud + q * 4 + 3, ex * v.w);
    }
}

// ---------------------------------------------------------------------------
// k5: per-node: node_embs = U2/s2 + b2; then P_src = emb @ Wm1[0:32,:],
//     P_dst = emb @ Wm1[32:64,:] + bm1. Psrc aliases h2g, Pdst aliases U2
//     (each thread reads its own U2 row before overwriting it).
__global__ void __launch_bounds__(256) k5_node(const float* __restrict__ s2,
                                               const float* __restrict__ b2,
                                               const float* __restrict__ Wm1,
                                               const float* __restrict__ bm1,
                                               float* __restrict__ Psrc,
                                               float* __restrict__ Pdst) {
    int n = blockIdx.x * blockDim.x + threadIdx.x;
    if (n >= NN) return;
    float inv = 1.f / (s2[n] + 1e-16f);
    float emb[32];
    const float4* ug = (const float4*)(Pdst + (size_t)n * 32);  // still holds U2
#pragma unroll
    for (int q = 0; q < 8; ++q) {
        float4 v = ug[q];
        emb[q * 4 + 0] = v.x * inv + b2[q * 4 + 0];
        emb[q * 4 + 1] = v.y * inv + b2[q * 4 + 1];
        emb[q * 4 + 2] = v.z * inv + b2[q * 4 + 2];
        emb[q * 4 + 3] = v.w * inv + b2[q * 4 + 3];
    }
    float ps[32], pd[32];
#pragma unroll
    for (int k = 0; k < 32; ++k) {
        ps[k] = 0.f;
        pd[k] = bm1[k];
    }
    for (int c = 0; c < 32; ++c) {
        float ec = emb[c];
#pragma unroll
        for (int k = 0; k < 32; ++k) {
            ps[k] += ec * Wm1[c * 32 + k];
            pd[k] += ec * Wm1[(32 + c) * 32 + k];
        }
    }
    float4* pso = (float4*)(Psrc + (size_t)n * 32);
    float4* pdo = (float4*)(Pdst + (size_t)n * 32);
#pragma unroll
    for (int q = 0; q < 8; ++q) {
        pso[q] = make_float4(ps[q * 4], ps[q * 4 + 1], ps[q * 4 + 2], ps[q * 4 + 3]);
        pdo[q] = make_float4(pd[q * 4], pd[q * 4 + 1], pd[q * 4 + 2], pd[q * 4 + 3]);
    }
}

// ---------------------------------------------------------------------------
// k6: per-edge MLP scorer on ORIGINAL edges.
__global__ void __launch_bounds__(256) k6_mlp(const int* __restrict__ ei,
                                              const float* __restrict__ ea,
                                              const float* __restrict__ Psrc,
                                              const float* __restrict__ Pdst,
                                              const float* __restrict__ Wm1,
                                              const float* __restrict__ Wm2,
                                              const float* __restrict__ bm2,
                                              const float* __restrict__ Wm3,
                                              const float* __restrict__ bm3,
                                              float* __restrict__ out) {
    int e = blockIdx.x * blockDim.x + threadIdx.x;
    if (e >= NE) return;
    int s = ei[e], d = ei[NE + e];
    float4 av = ((const float4*)ea)[e];
    float a4[4] = {av.x, av.y, av.z, av.w};
    float q[32];
    const float4* ps = (const float4*)(Psrc + (size_t)s * 32);
    const float4* pd = (const float4*)(Pdst + (size_t)d * 32);
#pragma unroll
    for (int qq = 0; qq < 8; ++qq) {
        float4 a_ = ps[qq];
        float4 b_ = pd[qq];
        q[qq * 4 + 0] = a_.x + b_.x;
        q[qq * 4 + 1] = a_.y + b_.y;
        q[qq * 4 + 2] = a_.z + b_.z;
        q[qq * 4 + 3] = a_.w + b_.w;
    }
#pragma unroll
    for (int j = 0; j < 4; ++j) {
        float aj = a4[j];
#pragma unroll
        for (int k = 0; k < 32; ++k) q[k] += aj * Wm1[(64 + j) * 32 + k];
    }
#pragma unroll
    for (int k = 0; k < 32; ++k) q[k] = fmaxf(q[k], 0.f);
    float acc[16];
#pragma unroll
    for (int t = 0; t < 16; ++t) acc[t] = bm2[t];
    for (int k = 0; k < 32; ++k) {
        float qk = q[k];
#pragma unroll
        for (int t = 0; t < 16; ++t) acc[t] += qk * Wm2[k * 16 + t];
    }
    float z = bm3[0];
#pragma unroll
    for (int t = 0; t < 16; ++t) z += fmaxf(acc[t], 0.f) * Wm3[t];
    out[e] = 1.f / (1.f + __expf(-z));
}

// ---------------------------------------------------------------------------
extern "C" void kernel_launch(void* const* d_in, const int* in_sizes, int n_in,
                              void* d_out, int out_size, void* d_ws, size_t ws_size,
                              hipStream_t stream) {
    const float* x   = (const float*)d_in[0];
    const int* ei    = (const int*)d_in[1];
    const float* ea  = (const float*)d_in[2];
    const float* W1  = (const float*)d_in[3];
    const float* as1 = (const float*)d_in[4];
    const float* ad1 = (const float*)d_in[5];
    const float* b1  = (const float*)d_in[6];
    const float* W2  = (const float*)d_in[7];
    const float* as2 = (const float*)d_in[8];
    const float* ad2 = (const float*)d_in[9];
    const float* b2  = (const float*)d_in[10];
    const float* Wm1 = (const float*)d_in[11];
    const float* bm1 = (const float*)d_in[12];
    const float* Wm2 = (const float*)d_in[13];
    const float* bm2 = (const float*)d_in[14];
    const float* Wm3 = (const float*)d_in[15];
    const float* bm3 = (const float*)d_in[16];
    float* out = (float*)d_out;

    char* ws = (char*)d_ws;
    float* sT   = (float*)(ws);                       // N*4 floats  = 1.6 MB
    float* h2g  = (float*)(ws + 1600000);             // N*32 floats = 12.8 MB (→ Psrc)
    float* U2   = (float*)(ws + 1600000 + 12800000);  // N*32 floats = 12.8 MB (→ Pdst)
    float* a2   = (float*)(ws + 1600000 + 25600000);  // N*2 floats  = 0.8 MB
    float* s2   = (float*)(ws + 1600000 + 26400000);  // N floats    = 0.4 MB
    float* c4   = (float*)(ws + 1600000 + 26800000);  // 4 floats

    const int NB = (NN + 255) / 256;
    const int EB = (NE + 255) / 256;

    hipLaunchKernelGGL(k0_consts, dim3(1), dim3(64), 0, stream, W1, as1, ad1, c4);
    hipLaunchKernelGGL(k1_init, dim3(NB), dim3(256), 0, stream, x, c4, sT);
    hipLaunchKernelGGL(k2_edge1, dim3(EB), dim3(256), 0, stream, ei, x, c4, sT);
    hipLaunchKernelGGL(k3_node, dim3(NB), dim3(256), 0, stream, sT, W1, b1, W2, as2, ad2,
                       h2g, (float2*)a2, s2, U2);
    hipLaunchKernelGGL(k4_edge2, dim3(EB), dim3(256), 0, stream, ei, h2g, (float2*)a2, s2, U2);
    hipLaunchKernelGGL(k5_node, dim3(NB), dim3(256), 0, stream, s2, b2, Wm1, bm1, h2g, U2);
    hipLaunchKernelGGL(k6_mlp, dim3(EB), dim3(256), 0, stream, ei, ea, h2g, U2, Wm1, Wm2,
                       bm2, Wm3, bm3, out);
}

// Round 2
// 924.146 us; speedup vs baseline: 6.9222x; 6.9222x over previous
//
#include <hip/hip_runtime.h>
#include <math.h>

#define NN 100000
#define NE 3200000
#define NEG 0.2f
#define NB_SCAN 391  // ceil(NN/256)

__device__ __forceinline__ float leaky(float v) { return v > 0.f ? v : NEG * v; }

// ---------------------------------------------------------------------------
// k0: layer-1 attention constants: c4 = {cs0, cs1, cd0, cd1}
__global__ void k0_consts(const float* __restrict__ W1, const float* __restrict__ as1,
                          const float* __restrict__ ad1, float* __restrict__ c4) {
    int h = threadIdx.x;
    if (h < 2) {
        float cs = 0.f, cd = 0.f;
        for (int c = 0; c < 32; ++c) {
            float w = W1[h * 32 + c];
            cs += w * as1[h * 32 + c];
            cd += w * ad1[h * 32 + c];
        }
        c4[h] = cs;
        c4[2 + h] = cd;
    }
}

// ---------------------------------------------------------------------------
// CSR build: histogram of dst degrees
__global__ void __launch_bounds__(256) kh_hist(const int* __restrict__ ei,
                                               int* __restrict__ deg) {
    int e = blockIdx.x * blockDim.x + threadIdx.x;
    if (e >= NE) return;
    atomicAdd(deg + ei[NE + e], 1);
}

// Block-level exclusive scan: rowstart[i] = local exclusive prefix; bsum[b] = block total
__global__ void __launch_bounds__(256) k_scan1(const int* __restrict__ deg,
                                               int* __restrict__ rowstart,
                                               int* __restrict__ bsum) {
    __shared__ int sh[256];
    int t = threadIdx.x;
    int idx = blockIdx.x * 256 + t;
    int v = (idx < NN) ? deg[idx] : 0;
    sh[t] = v;
    __syncthreads();
    for (int o = 1; o < 256; o <<= 1) {
        int add = (t >= o) ? sh[t - o] : 0;
        __syncthreads();
        sh[t] += add;
        __syncthreads();
    }
    if (idx < NN) rowstart[idx] = sh[t] - v;  // exclusive
    if (t == 255) bsum[blockIdx.x] = sh[255];
}

// Serial scan of 391 block sums (trivial)
__global__ void k_scan2(int* __restrict__ bsum, int* __restrict__ rowstart) {
    if (threadIdx.x == 0 && blockIdx.x == 0) {
        int run = 0;
        for (int i = 0; i < NB_SCAN; ++i) {
            int t = bsum[i];
            bsum[i] = run;
            run += t;
        }
        rowstart[NN] = run;  // == NE
    }
}

// Add block offsets; init fill cursor (reuses deg storage)
__global__ void __launch_bounds__(256) k_scan3(int* __restrict__ rowstart,
                                               const int* __restrict__ bsum,
                                               int* __restrict__ cursor) {
    int idx = blockIdx.x * 256 + threadIdx.x;
    if (idx >= NN) return;
    int rs = rowstart[idx] + bsum[idx >> 8];
    rowstart[idx] = rs;
    cursor[idx] = rs;
}

// Fill: srcidx grouped by dst
__global__ void __launch_bounds__(256) k_fill(const int* __restrict__ ei,
                                              int* __restrict__ cursor,
                                              int* __restrict__ srcidx) {
    int e = blockIdx.x * blockDim.x + threadIdx.x;
    if (e >= NE) return;
    int s = ei[e], d = ei[NE + e];
    int p = atomicAdd(cursor + d, 1);
    srcidx[p] = s;
}

// ---------------------------------------------------------------------------
// Layer-1 aggregation (gather). 16 lanes per node; r2[n] = {T0/s0, T1/s1}.
__global__ void __launch_bounds__(256) k_agg1(const int* __restrict__ rowstart,
                                              const int* __restrict__ srcidx,
                                              const float* __restrict__ x,
                                              const float* __restrict__ c4,
                                              float2* __restrict__ r2) {
    int gtid = blockIdx.x * blockDim.x + threadIdx.x;
    int n = gtid >> 4;
    int lane = gtid & 15;
    if (n >= NN) return;
    float c0 = c4[0], c1 = c4[1], c2 = c4[2], c3 = c4[3];
    float xd = x[n];
    float xdc2 = xd * c2, xdc3 = xd * c3;
    float s0 = 0.f, s1 = 0.f, t0 = 0.f, t1 = 0.f;
    int rs = rowstart[n], re = rowstart[n + 1];
    for (int i = rs + lane; i < re; i += 16) {
        float xs = x[srcidx[i]];
        float ex0 = __expf(leaky(xs * c0 + xdc2));
        float ex1 = __expf(leaky(xs * c1 + xdc3));
        s0 += ex0;
        s1 += ex1;
        t0 += ex0 * xs;
        t1 += ex1 * xs;
    }
#pragma unroll
    for (int m = 8; m >= 1; m >>= 1) {
        s0 += __shfl_xor(s0, m, 16);
        s1 += __shfl_xor(s1, m, 16);
        t0 += __shfl_xor(t0, m, 16);
        t1 += __shfl_xor(t1, m, 16);
    }
    if (lane == 0) {
        // self-loop
        float ex0 = __expf(leaky(xd * (c0 + c2)));
        float ex1 = __expf(leaky(xd * (c1 + c3)));
        s0 += ex0;
        s1 += ex1;
        t0 += ex0 * xd;
        t1 += ex1 * xd;
        r2[n] = make_float2(t0 / (s0 + 1e-16f), t1 / (s1 + 1e-16f));
    }
}

// ---------------------------------------------------------------------------
// k3: per-node layer-1 output -> h2 row + layer-2 attention scalars
__global__ void __launch_bounds__(256) k3_node(const float2* __restrict__ r2,
                                               const float* __restrict__ W1,
                                               const float* __restrict__ b1,
                                               const float* __restrict__ W2,
                                               const float* __restrict__ as2,
                                               const float* __restrict__ ad2,
                                               float* __restrict__ h2g,
                                               float2* __restrict__ a2) {
    int n = blockIdx.x * blockDim.x + threadIdx.x;
    if (n >= NN) return;
    float2 r = r2[n];
    float h2[32];
#pragma unroll
    for (int c = 0; c < 32; ++c) h2[c] = 0.f;
    for (int j = 0; j < 64; ++j) {
        float o = W1[j] * (j < 32 ? r.x : r.y) + b1[j];
        o = fmaxf(o, 0.f);
#pragma unroll
        for (int c = 0; c < 32; ++c) h2[c] += o * W2[j * 32 + c];
    }
    float asum = 0.f, adsum = 0.f;
#pragma unroll
    for (int c = 0; c < 32; ++c) {
        asum += h2[c] * as2[c];
        adsum += h2[c] * ad2[c];
    }
    a2[n] = make_float2(asum, adsum);
    float4* hg = (float4*)(h2g + (size_t)n * 32);
#pragma unroll
    for (int q = 0; q < 8; ++q)
        hg[q] = make_float4(h2[q * 4], h2[q * 4 + 1], h2[q * 4 + 2], h2[q * 4 + 3]);
}

// ---------------------------------------------------------------------------
// Layer-2 aggregation (gather). 32 lanes per node, lane = channel.
// emb[n,c] = (sum_e ex_e * h2[src_e, c]) / (sum_e ex_e) + b2[c]
__global__ void __launch_bounds__(256) k_agg2(const int* __restrict__ rowstart,
                                              const int* __restrict__ srcidx,
                                              const float* __restrict__ h2g,
                                              const float2* __restrict__ a2,
                                              const float* __restrict__ b2,
                                              float* __restrict__ emb) {
    int gtid = blockIdx.x * blockDim.x + threadIdx.x;
    int n = gtid >> 5;
    int c = gtid & 31;
    if (n >= NN) return;
    float2 an = a2[n];
    float adn = an.y;
    // self-loop
    float exn = __expf(leaky(an.x + adn));
    float u = exn * h2g[(size_t)n * 32 + c];
    float ssum = exn;
    int rs = rowstart[n], re = rowstart[n + 1];
    for (int i = rs; i < re; ++i) {
        int s = srcidx[i];
        float ex = __expf(leaky(a2[s].x + adn));
        u += ex * h2g[(size_t)s * 32 + c];
        ssum += ex;
    }
    emb[(size_t)n * 32 + c] = u / (ssum + 1e-16f) + b2[c];
}

// ---------------------------------------------------------------------------
// k5: per-node P_src = emb @ Wm1[0:32,:], P_dst = emb @ Wm1[32:64,:] + bm1
__global__ void __launch_bounds__(256) k5_node(const float* __restrict__ emb,
                                               const float* __restrict__ Wm1,
                                               const float* __restrict__ bm1,
                                               float* __restrict__ Psrc,
                                               float* __restrict__ Pdst) {
    int n = blockIdx.x * blockDim.x + threadIdx.x;
    if (n >= NN) return;
    float em[32];
    const float4* eg = (const float4*)(emb + (size_t)n * 32);
#pragma unroll
    for (int q = 0; q < 8; ++q) {
        float4 v = eg[q];
        em[q * 4 + 0] = v.x;
        em[q * 4 + 1] = v.y;
        em[q * 4 + 2] = v.z;
        em[q * 4 + 3] = v.w;
    }
    float ps[32], pd[32];
#pragma unroll
    for (int k = 0; k < 32; ++k) {
        ps[k] = 0.f;
        pd[k] = bm1[k];
    }
    for (int c = 0; c < 32; ++c) {
        float ec = em[c];
#pragma unroll
        for (int k = 0; k < 32; ++k) {
            ps[k] += ec * Wm1[c * 32 + k];
            pd[k] += ec * Wm1[(32 + c) * 32 + k];
        }
    }
    float4* pso = (float4*)(Psrc + (size_t)n * 32);
    float4* pdo = (float4*)(Pdst + (size_t)n * 32);
#pragma unroll
    for (int q = 0; q < 8; ++q) {
        pso[q] = make_float4(ps[q * 4], ps[q * 4 + 1], ps[q * 4 + 2], ps[q * 4 + 3]);
        pdo[q] = make_float4(pd[q * 4], pd[q * 4 + 1], pd[q * 4 + 2], pd[q * 4 + 3]);
    }
}

// ---------------------------------------------------------------------------
// k6: per-edge MLP scorer on ORIGINAL edges.
__global__ void __launch_bounds__(256) k6_mlp(const int* __restrict__ ei,
                                              const float* __restrict__ ea,
                                              const float* __restrict__ Psrc,
                                              const float* __restrict__ Pdst,
                                              const float* __restrict__ Wm1,
                                              const float* __restrict__ Wm2,
                                              const float* __restrict__ bm2,
                                              const float* __restrict__ Wm3,
                                              const float* __restrict__ bm3,
                                              float* __restrict__ out) {
    int e = blockIdx.x * blockDim.x + threadIdx.x;
    if (e >= NE) return;
    int s = ei[e], d = ei[NE + e];
    float4 av = ((const float4*)ea)[e];
    float a4[4] = {av.x, av.y, av.z, av.w};
    float q[32];
    const float4* ps = (const float4*)(Psrc + (size_t)s * 32);
    const float4* pd = (const float4*)(Pdst + (size_t)d * 32);
#pragma unroll
    for (int qq = 0; qq < 8; ++qq) {
        float4 a_ = ps[qq];
        float4 b_ = pd[qq];
        q[qq * 4 + 0] = a_.x + b_.x;
        q[qq * 4 + 1] = a_.y + b_.y;
        q[qq * 4 + 2] = a_.z + b_.z;
        q[qq * 4 + 3] = a_.w + b_.w;
    }
#pragma unroll
    for (int j = 0; j < 4; ++j) {
        float aj = a4[j];
#pragma unroll
        for (int k = 0; k < 32; ++k) q[k] += aj * Wm1[(64 + j) * 32 + k];
    }
#pragma unroll
    for (int k = 0; k < 32; ++k) q[k] = fmaxf(q[k], 0.f);
    float acc[16];
#pragma unroll
    for (int t = 0; t < 16; ++t) acc[t] = bm2[t];
    for (int k = 0; k < 32; ++k) {
        float qk = q[k];
#pragma unroll
        for (int t = 0; t < 16; ++t) acc[t] += qk * Wm2[k * 16 + t];
    }
    float z = bm3[0];
#pragma unroll
    for (int t = 0; t < 16; ++t) z += fmaxf(acc[t], 0.f) * Wm3[t];
    out[e] = 1.f / (1.f + __expf(-z));
}

// ---------------------------------------------------------------------------
extern "C" void kernel_launch(void* const* d_in, const int* in_sizes, int n_in,
                              void* d_out, int out_size, void* d_ws, size_t ws_size,
                              hipStream_t stream) {
    const float* x   = (const float*)d_in[0];
    const int* ei    = (const int*)d_in[1];
    const float* ea  = (const float*)d_in[2];
    const float* W1  = (const float*)d_in[3];
    const float* as1 = (const float*)d_in[4];
    const float* ad1 = (const float*)d_in[5];
    const float* b1  = (const float*)d_in[6];
    const float* W2  = (const float*)d_in[7];
    const float* as2 = (const float*)d_in[8];
    const float* ad2 = (const float*)d_in[9];
    const float* b2  = (const float*)d_in[10];
    const float* Wm1 = (const float*)d_in[11];
    const float* bm1 = (const float*)d_in[12];
    const float* Wm2 = (const float*)d_in[13];
    const float* bm2 = (const float*)d_in[14];
    const float* Wm3 = (const float*)d_in[15];
    const float* bm3 = (const float*)d_in[16];
    float* out = (float*)d_out;

    // workspace layout (bytes), total ~40.8 MB
    char* ws = (char*)d_ws;
    float* c4     = (float*)(ws + 0);          // 16 B (pad to 256)
    int*   deg    = (int*)  (ws + 256);        // NN*4 = 400000  (reused as cursor)
    int*   rowst  = (int*)  (ws + 400512);     // (NN+1)*4
    int*   bsum   = (int*)  (ws + 800768);     // NB_SCAN*4
    float* r2     = (float*)(ws + 802304);     // NN*8
    float* a2     = (float*)(ws + 1602304);    // NN*8
    int*   srcidx = (int*)  (ws + 2402304);    // NE*4 = 12800000 (-> Psrc after dead)
    float* h2g    = (float*)(ws + 15202304);   // NN*32*4 = 12800000 (-> Pdst after dead)
    float* emb    = (float*)(ws + 28002304);   // NN*32*4 = 12800000
    float* Psrc   = (float*)srcidx;
    float* Pdst   = h2g;

    const int NB = (NN + 255) / 256;
    const int EB = (NE + 255) / 256;

    hipMemsetAsync(deg, 0, NN * sizeof(int), stream);
    hipLaunchKernelGGL(k0_consts, dim3(1), dim3(64), 0, stream, W1, as1, ad1, c4);
    hipLaunchKernelGGL(kh_hist, dim3(EB), dim3(256), 0, stream, ei, deg);
    hipLaunchKernelGGL(k_scan1, dim3(NB_SCAN), dim3(256), 0, stream, deg, rowst, bsum);
    hipLaunchKernelGGL(k_scan2, dim3(1), dim3(64), 0, stream, bsum, rowst);
    hipLaunchKernelGGL(k_scan3, dim3(NB_SCAN), dim3(256), 0, stream, rowst, bsum, deg);
    hipLaunchKernelGGL(k_fill, dim3(EB), dim3(256), 0, stream, ei, deg, srcidx);
    hipLaunchKernelGGL(k_agg1, dim3((NN * 16 + 255) / 256), dim3(256), 0, stream,
                       rowst, srcidx, x, c4, (float2*)r2);
    hipLaunchKernelGGL(k3_node, dim3(NB), dim3(256), 0, stream, (float2*)r2, W1, b1, W2,
                       as2, ad2, h2g, (float2*)a2);
    hipLaunchKernelGGL(k_agg2, dim3((NN * 32 + 255) / 256), dim3(256), 0, stream,
                       rowst, srcidx, h2g, (float2*)a2, b2, emb);
    hipLaunchKernelGGL(k5_node, dim3(NB), dim3(256), 0, stream, emb, Wm1, bm1, Psrc, Pdst);
    hipLaunchKernelGGL(k6_mlp, dim3(EB), dim3(256), 0, stream, ei, ea, Psrc, Pdst, Wm1,
                       Wm2, bm2, Wm3, bm3, out);
}

// Round 3
// 619.770 us; speedup vs baseline: 10.3217x; 1.4911x over previous
//
#include <hip/hip_runtime.h>
#include <math.h>

#define NN 100000
#define NE 3200000
#define NEG 0.2f
#define NBKT 391   // ceil(NN/256) buckets of 256 nodes
#define TILE_E 8192

__device__ __forceinline__ float leaky(float v) { return v > 0.f ? v : NEG * v; }

// ---------------------------------------------------------------------------
// k0: layer-1 attention constants: c4 = {cs0, cs1, cd0, cd1}
__global__ void k0_consts(const float* __restrict__ W1, const float* __restrict__ as1,
                          const float* __restrict__ ad1, float* __restrict__ c4) {
    int h = threadIdx.x;
    if (h < 2) {
        float cs = 0.f, cd = 0.f;
        for (int c = 0; c < 32; ++c) {
            float w = W1[h * 32 + c];
            cs += w * as1[h * 32 + c];
            cd += w * ad1[h * 32 + c];
        }
        c4[h] = cs;
        c4[2 + h] = cd;
    }
}

// ---------------------------------------------------------------------------
// kA0: coarse histogram (LDS-privatized) of dst>>8 over 391 buckets
__global__ void __launch_bounds__(256) kA0_hist(const int* __restrict__ ei,
                                                int* __restrict__ bktcnt) {
    __shared__ int sh[NBKT];
    int t = threadIdx.x;
    for (int i = t; i < NBKT; i += 256) sh[i] = 0;
    __syncthreads();
    int base = blockIdx.x * TILE_E;
    int end = min(base + TILE_E, NE);
    for (int e = base + t; e < end; e += 256)
        atomicAdd(&sh[ei[NE + e] >> 8], 1);
    __syncthreads();
    for (int i = t; i < NBKT; i += 256)
        if (sh[i]) atomicAdd(&bktcnt[i], sh[i]);
}

// ---------------------------------------------------------------------------
// kscan: one-block exclusive scan of the 391 bucket counts
__global__ void __launch_bounds__(512) kscan(const int* __restrict__ bktcnt,
                                             int* __restrict__ bktoff,
                                             int* __restrict__ gcursor,
                                             int* __restrict__ rowst) {
    __shared__ int sh[512];
    int t = threadIdx.x;
    int v = (t < NBKT) ? bktcnt[t] : 0;
    sh[t] = v;
    __syncthreads();
    for (int o = 1; o < 512; o <<= 1) {
        int add = (t >= o) ? sh[t - o] : 0;
        __syncthreads();
        sh[t] += add;
        __syncthreads();
    }
    if (t < NBKT) {
        int excl = sh[t] - v;
        bktoff[t] = excl;
        gcursor[t] = excl;
    }
    if (t == 0) {
        bktoff[NBKT] = NE;
        rowst[NN] = NE;
    }
}

// ---------------------------------------------------------------------------
// kA1: partition edges into coarse buckets; ebuf[p] = (src<<8)|(dst&255)
__global__ void __launch_bounds__(256) kA1_part(const int* __restrict__ ei,
                                                int* __restrict__ gcursor,
                                                int* __restrict__ ebuf) {
    __shared__ int cnt[NBKT];
    __shared__ int cur[NBKT];
    int t = threadIdx.x;
    for (int i = t; i < NBKT; i += 256) cnt[i] = 0;
    __syncthreads();
    int base = blockIdx.x * TILE_E;
    int end = min(base + TILE_E, NE);
    for (int e = base + t; e < end; e += 256)
        atomicAdd(&cnt[ei[NE + e] >> 8], 1);
    __syncthreads();
    for (int i = t; i < NBKT; i += 256) {
        int c = cnt[i];
        cur[i] = c ? atomicAdd(&gcursor[i], c) : 0;
    }
    __syncthreads();
    for (int e = base + t; e < end; e += 256) {
        int s = ei[e], d = ei[NE + e];
        int p = atomicAdd(&cur[d >> 8], 1);
        ebuf[p] = (s << 8) | (d & 255);
    }
}

// ---------------------------------------------------------------------------
// kB: fine counting sort within each bucket (256 nodes); emits rowstart + srcidx
__global__ void __launch_bounds__(256) kB_sort(const int* __restrict__ bktoff,
                                               const int* __restrict__ ebuf,
                                               int* __restrict__ rowst,
                                               int* __restrict__ srcidx) {
    __shared__ int cnt[256];
    __shared__ int tmp[256];
    int b = blockIdx.x, t = threadIdx.x;
    int rs = bktoff[b], re = bktoff[b + 1];
    cnt[t] = 0;
    __syncthreads();
    for (int i = rs + t; i < re; i += 256)
        atomicAdd(&cnt[ebuf[i] & 255], 1);
    __syncthreads();
    int v = cnt[t];
    tmp[t] = v;
    __syncthreads();
    for (int o = 1; o < 256; o <<= 1) {
        int add = (t >= o) ? tmp[t - o] : 0;
        __syncthreads();
        tmp[t] += add;
        __syncthreads();
    }
    int excl = tmp[t] - v;
    int node = (b << 8) + t;
    if (node < NN) rowst[node] = rs + excl;
    cnt[t] = rs + excl;  // cursor
    __syncthreads();
    for (int i = rs + t; i < re; i += 256) {
        int e = ebuf[i];
        int p = atomicAdd(&cnt[e & 255], 1);
        srcidx[p] = e >> 8;
    }
}

// ---------------------------------------------------------------------------
// Layer-1 aggregation (gather). 16 lanes per node; r2[n] = {T0/s0, T1/s1}.
__global__ void __launch_bounds__(256) k_agg1(const int* __restrict__ rowstart,
                                              const int* __restrict__ srcidx,
                                              const float* __restrict__ x,
                                              const float* __restrict__ c4,
                                              float2* __restrict__ r2) {
    int gtid = blockIdx.x * blockDim.x + threadIdx.x;
    int n = gtid >> 4;
    int lane = gtid & 15;
    if (n >= NN) return;
    float c0 = c4[0], c1 = c4[1], c2 = c4[2], c3 = c4[3];
    float xd = x[n];
    float xdc2 = xd * c2, xdc3 = xd * c3;
    float s0 = 0.f, s1 = 0.f, t0 = 0.f, t1 = 0.f;
    int rs = rowstart[n], re = rowstart[n + 1];
    for (int i = rs + lane; i < re; i += 16) {
        float xs = x[srcidx[i]];
        float ex0 = __expf(leaky(xs * c0 + xdc2));
        float ex1 = __expf(leaky(xs * c1 + xdc3));
        s0 += ex0;
        s1 += ex1;
        t0 += ex0 * xs;
        t1 += ex1 * xs;
    }
#pragma unroll
    for (int m = 8; m >= 1; m >>= 1) {
        s0 += __shfl_xor(s0, m, 16);
        s1 += __shfl_xor(s1, m, 16);
        t0 += __shfl_xor(t0, m, 16);
        t1 += __shfl_xor(t1, m, 16);
    }
    if (lane == 0) {
        float ex0 = __expf(leaky(xd * (c0 + c2)));
        float ex1 = __expf(leaky(xd * (c1 + c3)));
        s0 += ex0;
        s1 += ex1;
        t0 += ex0 * xd;
        t1 += ex1 * xd;
        r2[n] = make_float2(t0 / (s0 + 1e-16f), t1 / (s1 + 1e-16f));
    }
}

// ---------------------------------------------------------------------------
// k3: per-node layer-1 output -> h2 row + layer-2 attention scalars
__global__ void __launch_bounds__(256) k3_node(const float2* __restrict__ r2,
                                               const float* __restrict__ W1,
                                               const float* __restrict__ b1,
                                               const float* __restrict__ W2,
                                               const float* __restrict__ as2,
                                               const float* __restrict__ ad2,
                                               float* __restrict__ h2g,
                                               float2* __restrict__ a2) {
    int n = blockIdx.x * blockDim.x + threadIdx.x;
    if (n >= NN) return;
    float2 r = r2[n];
    float h2[32];
#pragma unroll
    for (int c = 0; c < 32; ++c) h2[c] = 0.f;
    for (int j = 0; j < 64; ++j) {
        float o = W1[j] * (j < 32 ? r.x : r.y) + b1[j];
        o = fmaxf(o, 0.f);
#pragma unroll
        for (int c = 0; c < 32; ++c) h2[c] += o * W2[j * 32 + c];
    }
    float asum = 0.f, adsum = 0.f;
#pragma unroll
    for (int c = 0; c < 32; ++c) {
        asum += h2[c] * as2[c];
        adsum += h2[c] * ad2[c];
    }
    a2[n] = make_float2(asum, adsum);
    float4* hg = (float4*)(h2g + (size_t)n * 32);
#pragma unroll
    for (int q = 0; q < 8; ++q)
        hg[q] = make_float4(h2[q * 4], h2[q * 4 + 1], h2[q * 4 + 2], h2[q * 4 + 3]);
}

// ---------------------------------------------------------------------------
// Layer-2 aggregation (gather). 32 lanes per node, lane = channel.
__global__ void __launch_bounds__(256) k_agg2(const int* __restrict__ rowstart,
                                              const int* __restrict__ srcidx,
                                              const float* __restrict__ h2g,
                                              const float2* __restrict__ a2,
                                              const float* __restrict__ b2,
                                              float* __restrict__ emb) {
    int gtid = blockIdx.x * blockDim.x + threadIdx.x;
    int n = gtid >> 5;
    int c = gtid & 31;
    if (n >= NN) return;
    float2 an = a2[n];
    float adn = an.y;
    float exn = __expf(leaky(an.x + adn));
    float u = exn * h2g[(size_t)n * 32 + c];
    float ssum = exn;
    int rs = rowstart[n], re = rowstart[n + 1];
    for (int i = rs; i < re; ++i) {
        int s = srcidx[i];
        float ex = __expf(leaky(a2[s].x + adn));
        u += ex * h2g[(size_t)s * 32 + c];
        ssum += ex;
    }
    emb[(size_t)n * 32 + c] = u / (ssum + 1e-16f) + b2[c];
}

// ---------------------------------------------------------------------------
// k5: per-node P_src = emb @ Wm1[0:32,:], P_dst = emb @ Wm1[32:64,:] + bm1
__global__ void __launch_bounds__(256) k5_node(const float* __restrict__ emb,
                                               const float* __restrict__ Wm1,
                                               const float* __restrict__ bm1,
                                               float* __restrict__ Psrc,
                                               float* __restrict__ Pdst) {
    int n = blockIdx.x * blockDim.x + threadIdx.x;
    if (n >= NN) return;
    float em[32];
    const float4* eg = (const float4*)(emb + (size_t)n * 32);
#pragma unroll
    for (int q = 0; q < 8; ++q) {
        float4 v = eg[q];
        em[q * 4 + 0] = v.x;
        em[q * 4 + 1] = v.y;
        em[q * 4 + 2] = v.z;
        em[q * 4 + 3] = v.w;
    }
    float ps[32], pd[32];
#pragma unroll
    for (int k = 0; k < 32; ++k) {
        ps[k] = 0.f;
        pd[k] = bm1[k];
    }
    for (int c = 0; c < 32; ++c) {
        float ec = em[c];
#pragma unroll
        for (int k = 0; k < 32; ++k) {
            ps[k] += ec * Wm1[c * 32 + k];
            pd[k] += ec * Wm1[(32 + c) * 32 + k];
        }
    }
    float4* pso = (float4*)(Psrc + (size_t)n * 32);
    float4* pdo = (float4*)(Pdst + (size_t)n * 32);
#pragma unroll
    for (int q = 0; q < 8; ++q) {
        pso[q] = make_float4(ps[q * 4], ps[q * 4 + 1], ps[q * 4 + 2], ps[q * 4 + 3]);
        pdo[q] = make_float4(pd[q * 4], pd[q * 4 + 1], pd[q * 4 + 2], pd[q * 4 + 3]);
    }
}

// ---------------------------------------------------------------------------
// k6: per-edge MLP scorer on ORIGINAL edges.
__global__ void __launch_bounds__(256) k6_mlp(const int* __restrict__ ei,
                                              const float* __restrict__ ea,
                                              const float* __restrict__ Psrc,
                                              const float* __restrict__ Pdst,
                                              const float* __restrict__ Wm1,
                                              const float* __restrict__ Wm2,
                                              const float* __restrict__ bm2,
                                              const float* __restrict__ Wm3,
                                              const float* __restrict__ bm3,
                                              float* __restrict__ out) {
    int e = blockIdx.x * blockDim.x + threadIdx.x;
    if (e >= NE) return;
    int s = ei[e], d = ei[NE + e];
    float4 av = ((const float4*)ea)[e];
    float a4[4] = {av.x, av.y, av.z, av.w};
    float q[32];
    const float4* ps = (const float4*)(Psrc + (size_t)s * 32);
    const float4* pd = (const float4*)(Pdst + (size_t)d * 32);
#pragma unroll
    for (int qq = 0; qq < 8; ++qq) {
        float4 a_ = ps[qq];
        float4 b_ = pd[qq];
        q[qq * 4 + 0] = a_.x + b_.x;
        q[qq * 4 + 1] = a_.y + b_.y;
        q[qq * 4 + 2] = a_.z + b_.z;
        q[qq * 4 + 3] = a_.w + b_.w;
    }
#pragma unroll
    for (int j = 0; j < 4; ++j) {
        float aj = a4[j];
#pragma unroll
        for (int k = 0; k < 32; ++k) q[k] += aj * Wm1[(64 + j) * 32 + k];
    }
#pragma unroll
    for (int k = 0; k < 32; ++k) q[k] = fmaxf(q[k], 0.f);
    float acc[16];
#pragma unroll
    for (int t = 0; t < 16; ++t) acc[t] = bm2[t];
    for (int k = 0; k < 32; ++k) {
        float qk = q[k];
#pragma unroll
        for (int t = 0; t < 16; ++t) acc[t] += qk * Wm2[k * 16 + t];
    }
    float z = bm3[0];
#pragma unroll
    for (int t = 0; t < 16; ++t) z += fmaxf(acc[t], 0.f) * Wm3[t];
    out[e] = 1.f / (1.f + __expf(-z));
}

// ---------------------------------------------------------------------------
extern "C" void kernel_launch(void* const* d_in, const int* in_sizes, int n_in,
                              void* d_out, int out_size, void* d_ws, size_t ws_size,
                              hipStream_t stream) {
    const float* x   = (const float*)d_in[0];
    const int* ei    = (const int*)d_in[1];
    const float* ea  = (const float*)d_in[2];
    const float* W1  = (const float*)d_in[3];
    const float* as1 = (const float*)d_in[4];
    const float* ad1 = (const float*)d_in[5];
    const float* b1  = (const float*)d_in[6];
    const float* W2  = (const float*)d_in[7];
    const float* as2 = (const float*)d_in[8];
    const float* ad2 = (const float*)d_in[9];
    const float* b2  = (const float*)d_in[10];
    const float* Wm1 = (const float*)d_in[11];
    const float* bm1 = (const float*)d_in[12];
    const float* Wm2 = (const float*)d_in[13];
    const float* bm2 = (const float*)d_in[14];
    const float* Wm3 = (const float*)d_in[15];
    const float* bm3 = (const float*)d_in[16];
    float* out = (float*)d_out;

    // workspace layout (bytes), total ~40.4 MB
    char* ws = (char*)d_ws;
    float* c4      = (float*)(ws + 0);          // 16 B
    int*   bktcnt  = (int*)  (ws + 256);        // NBKT*4
    int*   bktoff  = (int*)  (ws + 2048);       // (NBKT+1)*4
    int*   gcursor = (int*)  (ws + 3840);       // NBKT*4
    int*   rowst   = (int*)  (ws + 5632);       // (NN+1)*4
    float* r2      = (float*)(ws + 405760);     // NN*8
    float* a2      = (float*)(ws + 1205760);    // NN*8
    int*   ebuf    = (int*)  (ws + 2005760);    // NE*4 (dead after kB -> h2g -> Psrc)
    int*   srcidx  = (int*)  (ws + 14805760);   // NE*4
    float* emb     = (float*)(ws + 27605760);   // NN*32*4 (k5 reads row then writes Pdst row)
    float* h2g     = (float*)ebuf;
    float* Psrc    = (float*)ebuf;
    float* Pdst    = emb;

    const int NB = (NN + 255) / 256;
    const int EB = (NE + 255) / 256;
    const int TB = (NE + TILE_E - 1) / TILE_E;  // 391

    hipMemsetAsync(bktcnt, 0, NBKT * sizeof(int), stream);
    hipLaunchKernelGGL(k0_consts, dim3(1), dim3(64), 0, stream, W1, as1, ad1, c4);
    hipLaunchKernelGGL(kA0_hist, dim3(TB), dim3(256), 0, stream, ei, bktcnt);
    hipLaunchKernelGGL(kscan, dim3(1), dim3(512), 0, stream, bktcnt, bktoff, gcursor, rowst);
    hipLaunchKernelGGL(kA1_part, dim3(TB), dim3(256), 0, stream, ei, gcursor, ebuf);
    hipLaunchKernelGGL(kB_sort, dim3(NBKT), dim3(256), 0, stream, bktoff, ebuf, rowst, srcidx);
    hipLaunchKernelGGL(k_agg1, dim3((NN * 16 + 255) / 256), dim3(256), 0, stream,
                       rowst, srcidx, x, c4, (float2*)r2);
    hipLaunchKernelGGL(k3_node, dim3(NB), dim3(256), 0, stream, (float2*)r2, W1, b1, W2,
                       as2, ad2, h2g, (float2*)a2);
    hipLaunchKernelGGL(k_agg2, dim3((NN * 32 + 255) / 256), dim3(256), 0, stream,
                       rowst, srcidx, h2g, (float2*)a2, b2, emb);
    hipLaunchKernelGGL(k5_node, dim3(NB), dim3(256), 0, stream, emb, Wm1, bm1, Psrc, Pdst);
    hipLaunchKernelGGL(k6_mlp, dim3(EB), dim3(256), 0, stream, ei, ea, Psrc, Pdst, Wm1,
                       Wm2, bm2, Wm3, bm3, out);
}

// Round 4
// 518.469 us; speedup vs baseline: 12.3384x; 1.1954x over previous
//
#include <hip/hip_runtime.h>
#include <math.h>

#define NN 100000
#define NE 3200000
#define NEG 0.2f
#define NBKT 391   // ceil(NN/256) buckets of 256 nodes
#define TILE_E 8192

__device__ __forceinline__ float leaky(float v) { return v > 0.f ? v : NEG * v; }

// bf16 helpers: RNE pack, exact unpack
__device__ __forceinline__ unsigned int f2bf(float f) {
    unsigned int u = __float_as_uint(f);
    return (u + 0x7fffu + ((u >> 16) & 1u)) >> 16;
}
__device__ __forceinline__ float bf2f(unsigned short h) {
    return __uint_as_float(((unsigned int)h) << 16);
}
__device__ __forceinline__ float bfl(unsigned int u) { return __uint_as_float(u << 16); }
__device__ __forceinline__ float bfh(unsigned int u) { return __uint_as_float(u & 0xffff0000u); }

// ---------------------------------------------------------------------------
// k0: layer-1 attention constants: c4 = {cs0, cs1, cd0, cd1}
__global__ void k0_consts(const float* __restrict__ W1, const float* __restrict__ as1,
                          const float* __restrict__ ad1, float* __restrict__ c4) {
    int h = threadIdx.x;
    if (h < 2) {
        float cs = 0.f, cd = 0.f;
        for (int c = 0; c < 32; ++c) {
            float w = W1[h * 32 + c];
            cs += w * as1[h * 32 + c];
            cd += w * ad1[h * 32 + c];
        }
        c4[h] = cs;
        c4[2 + h] = cd;
    }
}

// ---------------------------------------------------------------------------
// kA0: coarse histogram (LDS-privatized) of dst>>8 over 391 buckets
__global__ void __launch_bounds__(256) kA0_hist(const int* __restrict__ ei,
                                                int* __restrict__ bktcnt) {
    __shared__ int sh[NBKT];
    int t = threadIdx.x;
    for (int i = t; i < NBKT; i += 256) sh[i] = 0;
    __syncthreads();
    int base = blockIdx.x * TILE_E;
    int end = min(base + TILE_E, NE);
    for (int e = base + t; e < end; e += 256)
        atomicAdd(&sh[ei[NE + e] >> 8], 1);
    __syncthreads();
    for (int i = t; i < NBKT; i += 256)
        if (sh[i]) atomicAdd(&bktcnt[i], sh[i]);
}

// ---------------------------------------------------------------------------
// kscan: one-block exclusive scan of the 391 bucket counts
__global__ void __launch_bounds__(512) kscan(const int* __restrict__ bktcnt,
                                             int* __restrict__ bktoff,
                                             int* __restrict__ gcursor,
                                             int* __restrict__ rowst) {
    __shared__ int sh[512];
    int t = threadIdx.x;
    int v = (t < NBKT) ? bktcnt[t] : 0;
    sh[t] = v;
    __syncthreads();
    for (int o = 1; o < 512; o <<= 1) {
        int add = (t >= o) ? sh[t - o] : 0;
        __syncthreads();
        sh[t] += add;
        __syncthreads();
    }
    if (t < NBKT) {
        int excl = sh[t] - v;
        bktoff[t] = excl;
        gcursor[t] = excl;
    }
    if (t == 0) {
        bktoff[NBKT] = NE;
        rowst[NN] = NE;
    }
}

// ---------------------------------------------------------------------------
// kA1: partition edges into coarse buckets; ebuf[p] = (src<<8)|(dst&255)
__global__ void __launch_bounds__(256) kA1_part(const int* __restrict__ ei,
                                                int* __restrict__ gcursor,
                                                int* __restrict__ ebuf) {
    __shared__ int cnt[NBKT];
    __shared__ int cur[NBKT];
    int t = threadIdx.x;
    for (int i = t; i < NBKT; i += 256) cnt[i] = 0;
    __syncthreads();
    int base = blockIdx.x * TILE_E;
    int end = min(base + TILE_E, NE);
    for (int e = base + t; e < end; e += 256)
        atomicAdd(&cnt[ei[NE + e] >> 8], 1);
    __syncthreads();
    for (int i = t; i < NBKT; i += 256) {
        int c = cnt[i];
        cur[i] = c ? atomicAdd(&gcursor[i], c) : 0;
    }
    __syncthreads();
    for (int e = base + t; e < end; e += 256) {
        int s = ei[e], d = ei[NE + e];
        int p = atomicAdd(&cur[d >> 8], 1);
        ebuf[p] = (s << 8) | (d & 255);
    }
}

// ---------------------------------------------------------------------------
// kB: fine counting sort within each bucket (256 nodes); emits rowstart + srcidx
__global__ void __launch_bounds__(256) kB_sort(const int* __restrict__ bktoff,
                                               const int* __restrict__ ebuf,
                                               int* __restrict__ rowst,
                                               int* __restrict__ srcidx) {
    __shared__ int cnt[256];
    __shared__ int tmp[256];
    int b = blockIdx.x, t = threadIdx.x;
    int rs = bktoff[b], re = bktoff[b + 1];
    cnt[t] = 0;
    __syncthreads();
    for (int i = rs + t; i < re; i += 256)
        atomicAdd(&cnt[ebuf[i] & 255], 1);
    __syncthreads();
    int v = cnt[t];
    tmp[t] = v;
    __syncthreads();
    for (int o = 1; o < 256; o <<= 1) {
        int add = (t >= o) ? tmp[t - o] : 0;
        __syncthreads();
        tmp[t] += add;
        __syncthreads();
    }
    int excl = tmp[t] - v;
    int node = (b << 8) + t;
    if (node < NN) rowst[node] = rs + excl;
    cnt[t] = rs + excl;  // cursor
    __syncthreads();
    for (int i = rs + t; i < re; i += 256) {
        int e = ebuf[i];
        int p = atomicAdd(&cnt[e & 255], 1);
        srcidx[p] = e >> 8;
    }
}

// ---------------------------------------------------------------------------
// Layer-1 aggregation (gather). 16 lanes per node; r2[n] = {T0/s0, T1/s1}.
__global__ void __launch_bounds__(256) k_agg1(const int* __restrict__ rowstart,
                                              const int* __restrict__ srcidx,
                                              const float* __restrict__ x,
                                              const float* __restrict__ c4,
                                              float2* __restrict__ r2) {
    int gtid = blockIdx.x * blockDim.x + threadIdx.x;
    int n = gtid >> 4;
    int lane = gtid & 15;
    if (n >= NN) return;
    float c0 = c4[0], c1 = c4[1], c2 = c4[2], c3 = c4[3];
    float xd = x[n];
    float xdc2 = xd * c2, xdc3 = xd * c3;
    float s0 = 0.f, s1 = 0.f, t0 = 0.f, t1 = 0.f;
    int rs = rowstart[n], re = rowstart[n + 1];
    for (int i = rs + lane; i < re; i += 16) {
        float xs = x[srcidx[i]];
        float ex0 = __expf(leaky(xs * c0 + xdc2));
        float ex1 = __expf(leaky(xs * c1 + xdc3));
        s0 += ex0;
        s1 += ex1;
        t0 += ex0 * xs;
        t1 += ex1 * xs;
    }
#pragma unroll
    for (int m = 8; m >= 1; m >>= 1) {
        s0 += __shfl_xor(s0, m, 16);
        s1 += __shfl_xor(s1, m, 16);
        t0 += __shfl_xor(t0, m, 16);
        t1 += __shfl_xor(t1, m, 16);
    }
    if (lane == 0) {
        float ex0 = __expf(leaky(xd * (c0 + c2)));
        float ex1 = __expf(leaky(xd * (c1 + c3)));
        s0 += ex0;
        s1 += ex1;
        t0 += ex0 * xd;
        t1 += ex1 * xd;
        r2[n] = make_float2(t0 / (s0 + 1e-16f), t1 / (s1 + 1e-16f));
    }
}

// ---------------------------------------------------------------------------
// k3: per-node layer-1 output -> h2 row (bf16) + layer-2 attention scalars
__global__ void __launch_bounds__(256) k3_node(const float2* __restrict__ r2,
                                               const float* __restrict__ W1,
                                               const float* __restrict__ b1,
                                               const float* __restrict__ W2,
                                               const float* __restrict__ as2,
                                               const float* __restrict__ ad2,
                                               unsigned short* __restrict__ h2g,
                                               float2* __restrict__ a2) {
    int n = blockIdx.x * blockDim.x + threadIdx.x;
    if (n >= NN) return;
    float2 r = r2[n];
    float h2[32];
#pragma unroll
    for (int c = 0; c < 32; ++c) h2[c] = 0.f;
    for (int j = 0; j < 64; ++j) {
        float o = W1[j] * (j < 32 ? r.x : r.y) + b1[j];
        o = fmaxf(o, 0.f);
#pragma unroll
        for (int c = 0; c < 32; ++c) h2[c] += o * W2[j * 32 + c];
    }
    float asum = 0.f, adsum = 0.f;
#pragma unroll
    for (int c = 0; c < 32; ++c) {
        asum += h2[c] * as2[c];
        adsum += h2[c] * ad2[c];
    }
    a2[n] = make_float2(asum, adsum);
    uint4* hg = (uint4*)(h2g + (size_t)n * 32);
#pragma unroll
    for (int q = 0; q < 4; ++q) {
        uint4 o;
        o.x = f2bf(h2[q * 8 + 0]) | (f2bf(h2[q * 8 + 1]) << 16);
        o.y = f2bf(h2[q * 8 + 2]) | (f2bf(h2[q * 8 + 3]) << 16);
        o.z = f2bf(h2[q * 8 + 4]) | (f2bf(h2[q * 8 + 5]) << 16);
        o.w = f2bf(h2[q * 8 + 6]) | (f2bf(h2[q * 8 + 7]) << 16);
        hg[q] = o;
    }
}

// ---------------------------------------------------------------------------
// Layer-2 aggregation (gather). 32 lanes per node, lane = channel.
// Chunked: lane j computes ex for edge base+j (parallel random a2 loads, one
// exp per edge), then shuffle-broadcast (s_j, ex_j) for the row gather.
__global__ void __launch_bounds__(256) k_agg2(const int* __restrict__ rowstart,
                                              const int* __restrict__ srcidx,
                                              const unsigned short* __restrict__ h2g,
                                              const float2* __restrict__ a2,
                                              const float* __restrict__ b2,
                                              float* __restrict__ emb) {
    int gtid = blockIdx.x * blockDim.x + threadIdx.x;
    int n = gtid >> 5;
    int c = gtid & 31;
    if (n >= NN) return;
    float2 an = a2[n];
    float adn = an.y;
    float exn = __expf(leaky(an.x + adn));
    float u = exn * bf2f(h2g[(size_t)n * 32 + c]);
    float ssum = exn;
    int rs = rowstart[n], re = rowstart[n + 1];
    for (int base = rs; base < re; base += 32) {
        int cnt = re - base;
        if (cnt > 32) cnt = 32;
        int sj = 0;
        float exj = 0.f;
        if (c < cnt) {
            sj = srcidx[base + c];
            exj = __expf(leaky(a2[sj].x + adn));
        }
        if (cnt == 32) {
#pragma unroll
            for (int j = 0; j < 32; ++j) {
                float exb = __shfl(exj, j, 32);
                int sb = __shfl(sj, j, 32);
                u += exb * bf2f(h2g[(size_t)sb * 32 + c]);
                ssum += exb;
            }
        } else {
            for (int j = 0; j < cnt; ++j) {
                float exb = __shfl(exj, j, 32);
                int sb = __shfl(sj, j, 32);
                u += exb * bf2f(h2g[(size_t)sb * 32 + c]);
                ssum += exb;
            }
        }
    }
    emb[(size_t)n * 32 + c] = u / (ssum + 1e-16f) + b2[c];
}

// ---------------------------------------------------------------------------
// k5: per-node P_src = emb @ Wm1[0:32,:], P_dst = emb @ Wm1[32:64,:] + bm1
//     (both stored as bf16 rows, 64 B each)
__global__ void __launch_bounds__(256) k5_node(const float* __restrict__ emb,
                                               const float* __restrict__ Wm1,
                                               const float* __restrict__ bm1,
                                               unsigned short* __restrict__ Psrc,
                                               unsigned short* __restrict__ Pdst) {
    int n = blockIdx.x * blockDim.x + threadIdx.x;
    if (n >= NN) return;
    float em[32];
    const float4* eg = (const float4*)(emb + (size_t)n * 32);
#pragma unroll
    for (int q = 0; q < 8; ++q) {
        float4 v = eg[q];
        em[q * 4 + 0] = v.x;
        em[q * 4 + 1] = v.y;
        em[q * 4 + 2] = v.z;
        em[q * 4 + 3] = v.w;
    }
    float ps[32], pd[32];
#pragma unroll
    for (int k = 0; k < 32; ++k) {
        ps[k] = 0.f;
        pd[k] = bm1[k];
    }
    for (int c = 0; c < 32; ++c) {
        float ec = em[c];
#pragma unroll
        for (int k = 0; k < 32; ++k) {
            ps[k] += ec * Wm1[c * 32 + k];
            pd[k] += ec * Wm1[(32 + c) * 32 + k];
        }
    }
    uint4* pso = (uint4*)(Psrc + (size_t)n * 32);
    uint4* pdo = (uint4*)(Pdst + (size_t)n * 32);
#pragma unroll
    for (int q = 0; q < 4; ++q) {
        uint4 o;
        o.x = f2bf(ps[q * 8 + 0]) | (f2bf(ps[q * 8 + 1]) << 16);
        o.y = f2bf(ps[q * 8 + 2]) | (f2bf(ps[q * 8 + 3]) << 16);
        o.z = f2bf(ps[q * 8 + 4]) | (f2bf(ps[q * 8 + 5]) << 16);
        o.w = f2bf(ps[q * 8 + 6]) | (f2bf(ps[q * 8 + 7]) << 16);
        pso[q] = o;
        o.x = f2bf(pd[q * 8 + 0]) | (f2bf(pd[q * 8 + 1]) << 16);
        o.y = f2bf(pd[q * 8 + 2]) | (f2bf(pd[q * 8 + 3]) << 16);
        o.z = f2bf(pd[q * 8 + 4]) | (f2bf(pd[q * 8 + 5]) << 16);
        o.w = f2bf(pd[q * 8 + 6]) | (f2bf(pd[q * 8 + 7]) << 16);
        pdo[q] = o;
    }
}

// ---------------------------------------------------------------------------
// k6: per-edge MLP scorer on ORIGINAL edges; bf16 P-tables.
__global__ void __launch_bounds__(256) k6_mlp(const int* __restrict__ ei,
                                              const float* __restrict__ ea,
                                              const unsigned short* __restrict__ Psrc,
                                              const unsigned short* __restrict__ Pdst,
                                              const float* __restrict__ Wm1,
                                              const float* __restrict__ Wm2,
                                              const float* __restrict__ bm2,
                                              const float* __restrict__ Wm3,
                                              const float* __restrict__ bm3,
                                              float* __restrict__ out) {
    int e = blockIdx.x * blockDim.x + threadIdx.x;
    if (e >= NE) return;
    int s = ei[e], d = ei[NE + e];
    float4 av = ((const float4*)ea)[e];
    float a4[4] = {av.x, av.y, av.z, av.w};
    float q[32];
    const uint4* ps = (const uint4*)(Psrc + (size_t)s * 32);
    const uint4* pd = (const uint4*)(Pdst + (size_t)d * 32);
#pragma unroll
    for (int qq = 0; qq < 4; ++qq) {
        uint4 a_ = ps[qq];
        uint4 b_ = pd[qq];
        q[qq * 8 + 0] = bfl(a_.x) + bfl(b_.x);
        q[qq * 8 + 1] = bfh(a_.x) + bfh(b_.x);
        q[qq * 8 + 2] = bfl(a_.y) + bfl(b_.y);
        q[qq * 8 + 3] = bfh(a_.y) + bfh(b_.y);
        q[qq * 8 + 4] = bfl(a_.z) + bfl(b_.z);
        q[qq * 8 + 5] = bfh(a_.z) + bfh(b_.z);
        q[qq * 8 + 6] = bfl(a_.w) + bfl(b_.w);
        q[qq * 8 + 7] = bfh(a_.w) + bfh(b_.w);
    }
#pragma unroll
    for (int j = 0; j < 4; ++j) {
        float aj = a4[j];
#pragma unroll
        for (int k = 0; k < 32; ++k) q[k] += aj * Wm1[(64 + j) * 32 + k];
    }
#pragma unroll
    for (int k = 0; k < 32; ++k) q[k] = fmaxf(q[k], 0.f);
    float acc[16];
#pragma unroll
    for (int t = 0; t < 16; ++t) acc[t] = bm2[t];
    for (int k = 0; k < 32; ++k) {
        float qk = q[k];
#pragma unroll
        for (int t = 0; t < 16; ++t) acc[t] += qk * Wm2[k * 16 + t];
    }
    float z = bm3[0];
#pragma unroll
    for (int t = 0; t < 16; ++t) z += fmaxf(acc[t], 0.f) * Wm3[t];
    out[e] = 1.f / (1.f + __expf(-z));
}

// ---------------------------------------------------------------------------
extern "C" void kernel_launch(void* const* d_in, const int* in_sizes, int n_in,
                              void* d_out, int out_size, void* d_ws, size_t ws_size,
                              hipStream_t stream) {
    const float* x   = (const float*)d_in[0];
    const int* ei    = (const int*)d_in[1];
    const float* ea  = (const float*)d_in[2];
    const float* W1  = (const float*)d_in[3];
    const float* as1 = (const float*)d_in[4];
    const float* ad1 = (const float*)d_in[5];
    const float* b1  = (const float*)d_in[6];
    const float* W2  = (const float*)d_in[7];
    const float* as2 = (const float*)d_in[8];
    const float* ad2 = (const float*)d_in[9];
    const float* b2  = (const float*)d_in[10];
    const float* Wm1 = (const float*)d_in[11];
    const float* bm1 = (const float*)d_in[12];
    const float* Wm2 = (const float*)d_in[13];
    const float* bm2 = (const float*)d_in[14];
    const float* Wm3 = (const float*)d_in[15];
    const float* bm3 = (const float*)d_in[16];
    float* out = (float*)d_out;

    // workspace layout (bytes), total ~40.4 MB
    char* ws = (char*)d_ws;
    float* c4      = (float*)(ws + 0);          // 16 B
    int*   bktcnt  = (int*)  (ws + 256);        // NBKT*4
    int*   bktoff  = (int*)  (ws + 2048);       // (NBKT+1)*4
    int*   gcursor = (int*)  (ws + 3840);       // NBKT*4
    int*   rowst   = (int*)  (ws + 5632);       // (NN+1)*4
    float* r2      = (float*)(ws + 405760);     // NN*8
    float* a2      = (float*)(ws + 1205760);    // NN*8
    int*   ebuf    = (int*)  (ws + 2005760);    // NE*4; dead after kB ->
                                                //   h2g bf16 (6.4 MB) @ +0 (dead after k_agg2)
                                                //   Psrc bf16 (6.4 MB) @ +0, Pdst bf16 @ +6.4 MB
    int*   srcidx  = (int*)  (ws + 14805760);   // NE*4
    float* emb     = (float*)(ws + 27605760);   // NN*32*4
    unsigned short* h2g  = (unsigned short*)ebuf;
    unsigned short* Psrc = (unsigned short*)ebuf;
    unsigned short* Pdst = (unsigned short*)(ws + 2005760 + 6400000);

    const int NB = (NN + 255) / 256;
    const int EB = (NE + 255) / 256;
    const int TB = (NE + TILE_E - 1) / TILE_E;  // 391

    hipMemsetAsync(bktcnt, 0, NBKT * sizeof(int), stream);
    hipLaunchKernelGGL(k0_consts, dim3(1), dim3(64), 0, stream, W1, as1, ad1, c4);
    hipLaunchKernelGGL(kA0_hist, dim3(TB), dim3(256), 0, stream, ei, bktcnt);
    hipLaunchKernelGGL(kscan, dim3(1), dim3(512), 0, stream, bktcnt, bktoff, gcursor, rowst);
    hipLaunchKernelGGL(kA1_part, dim3(TB), dim3(256), 0, stream, ei, gcursor, ebuf);
    hipLaunchKernelGGL(kB_sort, dim3(NBKT), dim3(256), 0, stream, bktoff, ebuf, rowst, srcidx);
    hipLaunchKernelGGL(k_agg1, dim3((NN * 16 + 255) / 256), dim3(256), 0, stream,
                       rowst, srcidx, x, c4, (float2*)r2);
    hipLaunchKernelGGL(k3_node, dim3(NB), dim3(256), 0, stream, (float2*)r2, W1, b1, W2,
                       as2, ad2, h2g, (float2*)a2);
    hipLaunchKernelGGL(k_agg2, dim3((NN * 32 + 255) / 256), dim3(256), 0, stream,
                       rowst, srcidx, h2g, (float2*)a2, b2, emb);
    hipLaunchKernelGGL(k5_node, dim3(NB), dim3(256), 0, stream, emb, Wm1, bm1, Psrc, Pdst);
    hipLaunchKernelGGL(k6_mlp, dim3(EB), dim3(256), 0, stream, ei, ea, Psrc, Pdst, Wm1,
                       Wm2, bm2, Wm3, bm3, out);
}

// Round 5
// 478.753 us; speedup vs baseline: 13.3620x; 1.0830x over previous
//
#include <hip/hip_runtime.h>
#include <math.h>

#define NN 100000
#define NE 3200000
#define NEG 0.2f
#define NBKT 391   // ceil(NN/256) buckets of 256 nodes
#define TILE_E 8192
#define K6_G 16    // 16-edge groups per wave
#define K6_BLOCKS 3125  // 3125 blocks * 4 waves * 16 groups * 16 edges = 3.2M

typedef __attribute__((ext_vector_type(8))) short bf16x8;
typedef __attribute__((ext_vector_type(4))) float f32x4;

__device__ __forceinline__ float leaky(float v) { return v > 0.f ? v : NEG * v; }

// bf16 helpers: RNE pack, exact unpack
__device__ __forceinline__ unsigned int f2bf(float f) {
    unsigned int u = __float_as_uint(f);
    return (u + 0x7fffu + ((u >> 16) & 1u)) >> 16;
}
__device__ __forceinline__ float bf2f(unsigned short h) {
    return __uint_as_float(((unsigned int)h) << 16);
}

// ---------------------------------------------------------------------------
// k0: layer-1 attention constants: c4 = {cs0, cs1, cd0, cd1}
__global__ void k0_consts(const float* __restrict__ W1, const float* __restrict__ as1,
                          const float* __restrict__ ad1, float* __restrict__ c4) {
    int h = threadIdx.x;
    if (h < 2) {
        float cs = 0.f, cd = 0.f;
        for (int c = 0; c < 32; ++c) {
            float w = W1[h * 32 + c];
            cs += w * as1[h * 32 + c];
            cd += w * ad1[h * 32 + c];
        }
        c4[h] = cs;
        c4[2 + h] = cd;
    }
}

// ---------------------------------------------------------------------------
// kA0: coarse histogram (LDS-privatized) of dst>>8 over 391 buckets
__global__ void __launch_bounds__(256) kA0_hist(const int* __restrict__ ei,
                                                int* __restrict__ bktcnt) {
    __shared__ int sh[NBKT];
    int t = threadIdx.x;
    for (int i = t; i < NBKT; i += 256) sh[i] = 0;
    __syncthreads();
    int base = blockIdx.x * TILE_E;
    int end = min(base + TILE_E, NE);
    for (int e = base + t; e < end; e += 256)
        atomicAdd(&sh[ei[NE + e] >> 8], 1);
    __syncthreads();
    for (int i = t; i < NBKT; i += 256)
        if (sh[i]) atomicAdd(&bktcnt[i], sh[i]);
}

// ---------------------------------------------------------------------------
// kscan: one-block exclusive scan of the 391 bucket counts
__global__ void __launch_bounds__(512) kscan(const int* __restrict__ bktcnt,
                                             int* __restrict__ bktoff,
                                             int* __restrict__ gcursor,
                                             int* __restrict__ rowst) {
    __shared__ int sh[512];
    int t = threadIdx.x;
    int v = (t < NBKT) ? bktcnt[t] : 0;
    sh[t] = v;
    __syncthreads();
    for (int o = 1; o < 512; o <<= 1) {
        int add = (t >= o) ? sh[t - o] : 0;
        __syncthreads();
        sh[t] += add;
        __syncthreads();
    }
    if (t < NBKT) {
        int excl = sh[t] - v;
        bktoff[t] = excl;
        gcursor[t] = excl;
    }
    if (t == 0) {
        bktoff[NBKT] = NE;
        rowst[NN] = NE;
    }
}

// ---------------------------------------------------------------------------
// kA1: partition edges into coarse buckets; ebuf[p] = (src<<8)|(dst&255)
__global__ void __launch_bounds__(256) kA1_part(const int* __restrict__ ei,
                                                int* __restrict__ gcursor,
                                                int* __restrict__ ebuf) {
    __shared__ int cnt[NBKT];
    __shared__ int cur[NBKT];
    int t = threadIdx.x;
    for (int i = t; i < NBKT; i += 256) cnt[i] = 0;
    __syncthreads();
    int base = blockIdx.x * TILE_E;
    int end = min(base + TILE_E, NE);
    for (int e = base + t; e < end; e += 256)
        atomicAdd(&cnt[ei[NE + e] >> 8], 1);
    __syncthreads();
    for (int i = t; i < NBKT; i += 256) {
        int c = cnt[i];
        cur[i] = c ? atomicAdd(&gcursor[i], c) : 0;
    }
    __syncthreads();
    for (int e = base + t; e < end; e += 256) {
        int s = ei[e], d = ei[NE + e];
        int p = atomicAdd(&cur[d >> 8], 1);
        ebuf[p] = (s << 8) | (d & 255);
    }
}

// ---------------------------------------------------------------------------
// kB: fine counting sort within each bucket (256 nodes); emits rowstart + srcidx
__global__ void __launch_bounds__(256) kB_sort(const int* __restrict__ bktoff,
                                               const int* __restrict__ ebuf,
                                               int* __restrict__ rowst,
                                               int* __restrict__ srcidx) {
    __shared__ int cnt[256];
    __shared__ int tmp[256];
    int b = blockIdx.x, t = threadIdx.x;
    int rs = bktoff[b], re = bktoff[b + 1];
    cnt[t] = 0;
    __syncthreads();
    for (int i = rs + t; i < re; i += 256)
        atomicAdd(&cnt[ebuf[i] & 255], 1);
    __syncthreads();
    int v = cnt[t];
    tmp[t] = v;
    __syncthreads();
    for (int o = 1; o < 256; o <<= 1) {
        int add = (t >= o) ? tmp[t - o] : 0;
        __syncthreads();
        tmp[t] += add;
        __syncthreads();
    }
    int excl = tmp[t] - v;
    int node = (b << 8) + t;
    if (node < NN) rowst[node] = rs + excl;
    cnt[t] = rs + excl;  // cursor
    __syncthreads();
    for (int i = rs + t; i < re; i += 256) {
        int e = ebuf[i];
        int p = atomicAdd(&cnt[e & 255], 1);
        srcidx[p] = e >> 8;
    }
}

// ---------------------------------------------------------------------------
// Layer-1 aggregation (gather). 16 lanes per node; r2[n] = {T0/s0, T1/s1}.
__global__ void __launch_bounds__(256) k_agg1(const int* __restrict__ rowstart,
                                              const int* __restrict__ srcidx,
                                              const float* __restrict__ x,
                                              const float* __restrict__ c4,
                                              float2* __restrict__ r2) {
    int gtid = blockIdx.x * blockDim.x + threadIdx.x;
    int n = gtid >> 4;
    int lane = gtid & 15;
    if (n >= NN) return;
    float c0 = c4[0], c1 = c4[1], c2 = c4[2], c3 = c4[3];
    float xd = x[n];
    float xdc2 = xd * c2, xdc3 = xd * c3;
    float s0 = 0.f, s1 = 0.f, t0 = 0.f, t1 = 0.f;
    int rs = rowstart[n], re = rowstart[n + 1];
    for (int i = rs + lane; i < re; i += 16) {
        float xs = x[srcidx[i]];
        float ex0 = __expf(leaky(xs * c0 + xdc2));
        float ex1 = __expf(leaky(xs * c1 + xdc3));
        s0 += ex0;
        s1 += ex1;
        t0 += ex0 * xs;
        t1 += ex1 * xs;
    }
#pragma unroll
    for (int m = 8; m >= 1; m >>= 1) {
        s0 += __shfl_xor(s0, m, 16);
        s1 += __shfl_xor(s1, m, 16);
        t0 += __shfl_xor(t0, m, 16);
        t1 += __shfl_xor(t1, m, 16);
    }
    if (lane == 0) {
        float ex0 = __expf(leaky(xd * (c0 + c2)));
        float ex1 = __expf(leaky(xd * (c1 + c3)));
        s0 += ex0;
        s1 += ex1;
        t0 += ex0 * xd;
        t1 += ex1 * xd;
        r2[n] = make_float2(t0 / (s0 + 1e-16f), t1 / (s1 + 1e-16f));
    }
}

// ---------------------------------------------------------------------------
// k3: per-node layer-1 output -> h2 row (bf16) + layer-2 attention scalars
__global__ void __launch_bounds__(256) k3_node(const float2* __restrict__ r2,
                                               const float* __restrict__ W1,
                                               const float* __restrict__ b1,
                                               const float* __restrict__ W2,
                                               const float* __restrict__ as2,
                                               const float* __restrict__ ad2,
                                               unsigned short* __restrict__ h2g,
                                               float2* __restrict__ a2) {
    int n = blockIdx.x * blockDim.x + threadIdx.x;
    if (n >= NN) return;
    float2 r = r2[n];
    float h2[32];
#pragma unroll
    for (int c = 0; c < 32; ++c) h2[c] = 0.f;
    for (int j = 0; j < 64; ++j) {
        float o = W1[j] * (j < 32 ? r.x : r.y) + b1[j];
        o = fmaxf(o, 0.f);
#pragma unroll
        for (int c = 0; c < 32; ++c) h2[c] += o * W2[j * 32 + c];
    }
    float asum = 0.f, adsum = 0.f;
#pragma unroll
    for (int c = 0; c < 32; ++c) {
        asum += h2[c] * as2[c];
        adsum += h2[c] * ad2[c];
    }
    a2[n] = make_float2(asum, adsum);
    uint4* hg = (uint4*)(h2g + (size_t)n * 32);
#pragma unroll
    for (int q = 0; q < 4; ++q) {
        uint4 o;
        o.x = f2bf(h2[q * 8 + 0]) | (f2bf(h2[q * 8 + 1]) << 16);
        o.y = f2bf(h2[q * 8 + 2]) | (f2bf(h2[q * 8 + 3]) << 16);
        o.z = f2bf(h2[q * 8 + 4]) | (f2bf(h2[q * 8 + 5]) << 16);
        o.w = f2bf(h2[q * 8 + 6]) | (f2bf(h2[q * 8 + 7]) << 16);
        hg[q] = o;
    }
}

// ---------------------------------------------------------------------------
// Layer-2 aggregation (gather). 32 lanes per node, lane = channel.
// Output: emb as bf16 rows (single 6.4 MB gather table for the edge scorer).
__global__ void __launch_bounds__(256) k_agg2(const int* __restrict__ rowstart,
                                              const int* __restrict__ srcidx,
                                              const unsigned short* __restrict__ h2g,
                                              const float2* __restrict__ a2,
                                              const float* __restrict__ b2,
                                              unsigned short* __restrict__ embq) {
    int gtid = blockIdx.x * blockDim.x + threadIdx.x;
    int n = gtid >> 5;
    int c = gtid & 31;
    if (n >= NN) return;
    float2 an = a2[n];
    float adn = an.y;
    float exn = __expf(leaky(an.x + adn));
    float u = exn * bf2f(h2g[(size_t)n * 32 + c]);
    float ssum = exn;
    int rs = rowstart[n], re = rowstart[n + 1];
    for (int base = rs; base < re; base += 32) {
        int cnt = re - base;
        if (cnt > 32) cnt = 32;
        int sj = 0;
        float exj = 0.f;
        if (c < cnt) {
            sj = srcidx[base + c];
            exj = __expf(leaky(a2[sj].x + adn));
        }
        if (cnt == 32) {
#pragma unroll
            for (int j = 0; j < 32; ++j) {
                float exb = __shfl(exj, j, 32);
                int sb = __shfl(sj, j, 32);
                u += exb * bf2f(h2g[(size_t)sb * 32 + c]);
                ssum += exb;
            }
        } else {
            for (int j = 0; j < cnt; ++j) {
                float exb = __shfl(exj, j, 32);
                int sb = __shfl(sj, j, 32);
                u += exb * bf2f(h2g[(size_t)sb * 32 + c]);
                ssum += exb;
            }
        }
    }
    embq[(size_t)n * 32 + c] = (unsigned short)f2bf(u / (ssum + 1e-16f) + b2[c]);
}

// ---------------------------------------------------------------------------
// k6: MFMA edge scorer. Per 16 edges: A = [emb_s | emb_d | ea | pad] (K=96),
// layer1 = 6 MFMA (2 N-tiles x 3 K-chunks), LDS C->A relayout, layer2 = 1 MFMA,
// shuffle-reduce + sigmoid epilogue.
// Layouts (gfx950 mfma_f32_16x16x32_bf16): A[m=lane&15][k=quad*8+j];
// B[k=quad*8+j][n=lane&15]; C/D col=lane&15, row=quad*4+reg.
__global__ void __launch_bounds__(256) k6_mfma(const int* __restrict__ ei,
                                               const float* __restrict__ ea,
                                               const unsigned short* __restrict__ embq,
                                               const float* __restrict__ Wm1,
                                               const float* __restrict__ bm1,
                                               const float* __restrict__ Wm2,
                                               const float* __restrict__ bm2,
                                               const float* __restrict__ Wm3,
                                               const float* __restrict__ bm3,
                                               float* __restrict__ out) {
    __shared__ unsigned short ldsq[4 * 16 * 40];  // per-wave 16x32 tile, stride 40
    int tid = threadIdx.x;
    int wave = tid >> 6, lane = tid & 63;
    int m = lane & 15, quad = lane >> 4;
    unsigned short* myl = ldsq + wave * (16 * 40);

    // per-wave weight fragments (bf16 bits in shorts)
    bf16x8 B1[3][2];
#pragma unroll
    for (int c = 0; c < 3; ++c) {
#pragma unroll
        for (int t = 0; t < 2; ++t) {
            bf16x8 v;
#pragma unroll
            for (int j = 0; j < 8; ++j) {
                int kk = c * 32 + quad * 8 + j;
                float w = (kk < 68) ? Wm1[kk * 32 + t * 16 + m] : 0.f;
                v[j] = (short)f2bf(w);
            }
            B1[c][t] = v;
        }
    }
    bf16x8 B2;
#pragma unroll
    for (int j = 0; j < 8; ++j)
        B2[j] = (short)f2bf(Wm2[(quad * 8 + j) * 16 + m]);
    float bl = bm1[m], bh = bm1[16 + m];
    float b2v = bm2[m], w3v = Wm3[m], b3 = bm3[0];

    int gw = blockIdx.x * 4 + wave;
    for (int i = 0; i < K6_G; ++i) {
        int ebase = (gw * K6_G + i) * 16;
        int e = ebase + m;
        int s = ei[e], d = ei[NE + e];
        bf16x8 a0 = *(const bf16x8*)(embq + (size_t)s * 32 + quad * 8);
        bf16x8 a1 = *(const bf16x8*)(embq + (size_t)d * 32 + quad * 8);
        bf16x8 a2v = {0, 0, 0, 0, 0, 0, 0, 0};
        if (quad == 0) {
            float4 av = ((const float4*)ea)[e];
            a2v[0] = (short)f2bf(av.x);
            a2v[1] = (short)f2bf(av.y);
            a2v[2] = (short)f2bf(av.z);
            a2v[3] = (short)f2bf(av.w);
        }
        f32x4 accL = {0.f, 0.f, 0.f, 0.f};
        f32x4 accH = {0.f, 0.f, 0.f, 0.f};
        accL = __builtin_amdgcn_mfma_f32_16x16x32_bf16(a0, B1[0][0], accL, 0, 0, 0);
        accH = __builtin_amdgcn_mfma_f32_16x16x32_bf16(a0, B1[0][1], accH, 0, 0, 0);
        accL = __builtin_amdgcn_mfma_f32_16x16x32_bf16(a1, B1[1][0], accL, 0, 0, 0);
        accH = __builtin_amdgcn_mfma_f32_16x16x32_bf16(a1, B1[1][1], accH, 0, 0, 0);
        accL = __builtin_amdgcn_mfma_f32_16x16x32_bf16(a2v, B1[2][0], accL, 0, 0, 0);
        accH = __builtin_amdgcn_mfma_f32_16x16x32_bf16(a2v, B1[2][1], accH, 0, 0, 0);
        // bias + relu + bf16, write C layout -> LDS [row][ch]
#pragma unroll
        for (int r = 0; r < 4; ++r) {
            int row = quad * 4 + r;
            myl[row * 40 + m] = (unsigned short)f2bf(fmaxf(accL[r] + bl, 0.f));
            myl[row * 40 + 16 + m] = (unsigned short)f2bf(fmaxf(accH[r] + bh, 0.f));
        }
        asm volatile("s_waitcnt lgkmcnt(0)" ::: "memory");
        bf16x8 aq = *(const bf16x8*)(myl + m * 40 + quad * 8);
        asm volatile("" ::: "memory");
        f32x4 accO = {0.f, 0.f, 0.f, 0.f};
        accO = __builtin_amdgcn_mfma_f32_16x16x32_bf16(aq, B2, accO, 0, 0, 0);
        // epilogue: relu, *Wm3[ch], reduce over 16 channels, sigmoid
        float z0, z1, z2, z3;
        {
            float v0 = fmaxf(accO[0] + b2v, 0.f) * w3v;
            float v1 = fmaxf(accO[1] + b2v, 0.f) * w3v;
            float v2 = fmaxf(accO[2] + b2v, 0.f) * w3v;
            float v3 = fmaxf(accO[3] + b2v, 0.f) * w3v;
#pragma unroll
            for (int mm = 8; mm >= 1; mm >>= 1) {
                v0 += __shfl_xor(v0, mm, 16);
                v1 += __shfl_xor(v1, mm, 16);
                v2 += __shfl_xor(v2, mm, 16);
                v3 += __shfl_xor(v3, mm, 16);
            }
            z0 = 1.f / (1.f + __expf(-(v0 + b3)));
            z1 = 1.f / (1.f + __expf(-(v1 + b3)));
            z2 = 1.f / (1.f + __expf(-(v2 + b3)));
            z3 = 1.f / (1.f + __expf(-(v3 + b3)));
        }
        if (m == 0)
            ((float4*)(out + ebase + quad * 4))[0] = make_float4(z0, z1, z2, z3);
    }
}

// ---------------------------------------------------------------------------
extern "C" void kernel_launch(void* const* d_in, const int* in_sizes, int n_in,
                              void* d_out, int out_size, void* d_ws, size_t ws_size,
                              hipStream_t stream) {
    const float* x   = (const float*)d_in[0];
    const int* ei    = (const int*)d_in[1];
    const float* ea  = (const float*)d_in[2];
    const float* W1  = (const float*)d_in[3];
    const float* as1 = (const float*)d_in[4];
    const float* ad1 = (const float*)d_in[5];
    const float* b1  = (const float*)d_in[6];
    const float* W2  = (const float*)d_in[7];
    const float* as2 = (const float*)d_in[8];
    const float* ad2 = (const float*)d_in[9];
    const float* b2  = (const float*)d_in[10];
    const float* Wm1 = (const float*)d_in[11];
    const float* bm1 = (const float*)d_in[12];
    const float* Wm2 = (const float*)d_in[13];
    const float* bm2 = (const float*)d_in[14];
    const float* Wm3 = (const float*)d_in[15];
    const float* bm3 = (const float*)d_in[16];
    float* out = (float*)d_out;

    // workspace layout (bytes)
    char* ws = (char*)d_ws;
    float* c4      = (float*)(ws + 0);          // 16 B
    int*   bktcnt  = (int*)  (ws + 256);        // NBKT*4
    int*   bktoff  = (int*)  (ws + 2048);       // (NBKT+1)*4
    int*   gcursor = (int*)  (ws + 3840);       // NBKT*4
    int*   rowst   = (int*)  (ws + 5632);       // (NN+1)*4
    float* r2      = (float*)(ws + 405760);     // NN*8
    float* a2      = (float*)(ws + 1205760);    // NN*8
    int*   ebuf    = (int*)  (ws + 2005760);    // NE*4; h2g bf16 aliases after kB
    int*   srcidx  = (int*)  (ws + 14805760);   // NE*4
    unsigned short* h2g  = (unsigned short*)ebuf;            // 6.4 MB (dead after k_agg2)
    unsigned short* embq = (unsigned short*)(ws + 27605760); // NN*32*2 = 6.4 MB

    const int NB = (NN + 255) / 256;
    const int TB = (NE + TILE_E - 1) / TILE_E;  // 391

    hipMemsetAsync(bktcnt, 0, NBKT * sizeof(int), stream);
    hipLaunchKernelGGL(k0_consts, dim3(1), dim3(64), 0, stream, W1, as1, ad1, c4);
    hipLaunchKernelGGL(kA0_hist, dim3(TB), dim3(256), 0, stream, ei, bktcnt);
    hipLaunchKernelGGL(kscan, dim3(1), dim3(512), 0, stream, bktcnt, bktoff, gcursor, rowst);
    hipLaunchKernelGGL(kA1_part, dim3(TB), dim3(256), 0, stream, ei, gcursor, ebuf);
    hipLaunchKernelGGL(kB_sort, dim3(NBKT), dim3(256), 0, stream, bktoff, ebuf, rowst, srcidx);
    hipLaunchKernelGGL(k_agg1, dim3((NN * 16 + 255) / 256), dim3(256), 0, stream,
                       rowst, srcidx, x, c4, (float2*)r2);
    hipLaunchKernelGGL(k3_node, dim3(NB), dim3(256), 0, stream, (float2*)r2, W1, b1, W2,
                       as2, ad2, h2g, (float2*)a2);
    hipLaunchKernelGGL(k_agg2, dim3((NN * 32 + 255) / 256), dim3(256), 0, stream,
                       rowst, srcidx, h2g, (float2*)a2, b2, embq);
    hipLaunchKernelGGL(k6_mfma, dim3(K6_BLOCKS), dim3(256), 0, stream, ei, ea, embq,
                       Wm1, bm1, Wm2, bm2, Wm3, bm3, out);
}